// Round 11
// baseline (120.108 us; speedup 1.0000x reference)
//
#include <hip/hip_runtime.h>

// RNNAdder round 10: r8 numerics VERBATIM (unscaled W, cvt-based hi/lo split,
// packed-pair ring, spread projection), scheduling-only changes:
//  (1) phase templated on SB (0/8): all ring offsets are compile-time imms
//      on one base VGPR (r8's runtime `sb` forced per-step address VALU).
//  (2) recurrence = 4 independent MFMA partials + tree add (depth 1).
//  (3) DS order by criticality: A-reads FIRST, then LUT gather (t+1, mask
//      already in reg), then np read (t+2). r9 regressed 330cy/step by
//      putting the gather ahead of the A-reads (in-order DS pipe).
//  (4) projection read bases precomputed; slot term is an immediate.

typedef _Float16 half8 __attribute__((ext_vector_type(8)));
typedef __fp16 fp16x2 __attribute__((ext_vector_type(2)));
typedef float floatx4 __attribute__((ext_vector_type(4)));

#define MFMA16(A, B, C) __builtin_amdgcn_mfma_f32_16x16x32_f16((A), (B), (C), 0, 0, 0)
#define BARRIER() asm volatile("s_waitcnt lgkmcnt(0)\n\ts_barrier" ::: "memory")

// pool dword layout (r8's): ring 16 slots x 16 rows x 68 dw | LUT | np
#define LUT_DW  17408
#define NP_DW   18432
#define POOL_DW 20512                 // 82 KB

template <int SB, bool PROJ>
__device__ __forceinline__ void steps8(
    int* __restrict__ pool, const int* __restrict__ lutI,
    const int* __restrict__ npP,
    const half8 (&Wint)[4], const half8 (&Wdint)[4], const half8& Pf,
    floatx4& Cxp, int& mkN,
    const int rBase, const int wBase, const int qs,
    const int (&projBase)[2], const float bdv, const bool cLt10,
    float* (&outP)[2][4])
{
    const floatx4 zero4 = {0.f, 0.f, 0.f, 0.f};
    #pragma unroll
    for (int i = 0; i < 8; ++i) {
        const int spw = SB + i;
        const int spr = (i == 0) ? ((SB ^ 8) + 7) : (SB + i - 1);

        // critical A-reads FIRST (in-order DS pipe)
        half8 A0 = *(const half8*)&pool[spr * 1088 + rBase];
        half8 A1 = *(const half8*)&pool[spr * 1088 + rBase + 16];
        half8 A2 = *(const half8*)&pool[spr * 1088 + rBase + 32];
        half8 A3 = *(const half8*)&pool[spr * 1088 + rBase + 48];
        // then the t+1 one-hot gather (mask in reg) and t+2 np read
        half8 Aoh = *(const half8*)&lutI[((mkN >> qs) & 0xFF) * 4];
        int mkN2 = npP[(i + 2) * 16];

        // recurrence: 4 independent partials (chain depth 1)
        floatx4 Ca = MFMA16(A0, Wint[0], Cxp);
        floatx4 Cb = MFMA16(A1, Wint[1], zero4);
        floatx4 Cc = MFMA16(A2, Wint[2], zero4);
        floatx4 Cd = MFMA16(A3, Wint[3], zero4);
        // xp for t+1 (independent; latency hides under tanh)
        Cxp = MFMA16(Aoh, Pf, zero4);
        mkN = mkN2;

        // tanh + pack (r8 value path verbatim)
        float hv[4];
        #pragma unroll
        for (int r = 0; r < 4; ++r) {
            float x  = (Ca[r] + Cb[r]) + (Cc[r] + Cd[r]);
            float e2 = __builtin_amdgcn_exp2f(x * 2.885390081777927f);
            hv[r] = 1.f - 2.f * __builtin_amdgcn_rcpf(e2 + 1.f);
        }
        #pragma unroll
        for (int p = 0; p < 2; ++p) {
            fp16x2 ph = __builtin_amdgcn_cvt_pkrtz(hv[2 * p], hv[2 * p + 1]);
            float c0 = (float)ph[0];
            float c1 = (float)ph[1];
            fp16x2 pl = __builtin_amdgcn_cvt_pkrtz((hv[2 * p] - c0) * 64.f,
                                                   (hv[2 * p + 1] - c1) * 64.f);
            unsigned phu = __builtin_bit_cast(unsigned, ph);
            unsigned plu = __builtin_bit_cast(unsigned, pl);
            unsigned w0 = __builtin_amdgcn_perm(plu, phu, 0x05040100u);
            unsigned w1 = __builtin_amdgcn_perm(plu, phu, 0x07060302u);
            pool[spw * 1088 + wBase + (2 * p) * 68]     = (int)w0;
            pool[spw * 1088 + wBase + (2 * p + 1) * 68] = (int)w1;
        }

        // spread projection: u=0 at i==2, u=1 at i==6 (prev phase's slots)
        if (PROJ && (i == 2 || i == 6)) {
            const int u = (i == 6) ? 1 : 0;        // compile-time after unroll
            const int sl = projBase[u] + (SB ^ 8) * 1088;
            half8 P0 = *(const half8*)&pool[sl];
            half8 P1 = *(const half8*)&pool[sl + 16];
            half8 P2 = *(const half8*)&pool[sl + 32];
            half8 P3 = *(const half8*)&pool[sl + 48];
            floatx4 Cp = MFMA16(P0, Wdint[0], zero4);
            Cp         = MFMA16(P1, Wdint[1], Cp);
            Cp         = MFMA16(P2, Wdint[2], Cp);
            Cp         = MFMA16(P3, Wdint[3], Cp);
            if (cLt10) {
                #pragma unroll
                for (int r = 0; r < 4; ++r)
                    outP[u][r][-80] = Cp[r] + bdv;
            }
        }

        BARRIER();   // lgkmcnt-only: global stores stay in flight
    }
}

__global__ __launch_bounds__(256)
void rnn_mfma(const int* __restrict__ num1, const int* __restrict__ num2,
              const float* __restrict__ E, const float* __restrict__ Wxh,
              const float* __restrict__ Whh, const float* __restrict__ bias,
              const float* __restrict__ Wd, const float* __restrict__ bd,
              float* __restrict__ out)
{
    __shared__ __align__(16) int pool[POOL_DW];
    int* lutI  = pool + LUT_DW;
    int* numpk = pool + NP_DW;

    const int tid  = threadIdx.x;
    const int w    = tid >> 6;
    const int lane = tid & 63;
    const int c    = lane & 15;
    const int q    = lane >> 4;
    const int qs   = q * 8;
    const int g    = blockIdx.x;

    // ---- startup staging (overlaid on ring slots 0..5) ----
    float* WhhS = (float*)pool;           // 4096
    float* P1t  = (float*)(pool + 4096);  // 640
    float* P2t  = (float*)(pool + 4736);  // 640
    float* WdS  = (float*)(pool + 5376);  // 640
    for (int i = tid; i < 4096; i += 256) WhhS[i] = Whh[i];
    for (int i = tid; i < 640;  i += 256) WdS[i]  = Wd[i];
    for (int idx = tid; idx < 640; idx += 256) {
        int v = idx >> 6, jj = idx & 63;
        float s1 = bias[jj], s2 = 0.f;
        #pragma unroll
        for (int i = 0; i < 32; ++i) {
            float e = E[v * 32 + i];
            s1 = fmaf(e, Wxh[i * 64 + jj], s1);
            s2 = fmaf(e, Wxh[(32 + i) * 64 + jj], s2);
        }
        P1t[idx] = s1;  // bias folded in
        P2t[idx] = s2;
    }
    {   // one-hot LUT: 256 entries x 4 dw
        int e = tid;
        #pragma unroll
        for (int j = 0; j < 4; ++j)
            lutI[e * 4 + j] = (((e >> (2 * j)) & 1) ? 0x3C00 : 0)
                            | (((e >> (2 * j + 1)) & 1) ? 0x3C000000 : 0);
    }
    // token bit-masks (rows 128..129 zero-padded)
    for (int idx = tid; idx < 2080; idx += 256) {
        int m = idx & 15, t = idx >> 4;
        int s = g * 16 + m;
        numpk[t * 16 + m] = (t < 128)
            ? ((1 << num1[s * 128 + t]) | (1 << (num2[s * 128 + t] + 10))) : 0;
    }
    __syncthreads();

    // ---- resident B-fragments (r8 verbatim: UNSCALED W) ----
    half8 Wint[4], Wdint[4], Pf;
    #pragma unroll
    for (int kt = 0; kt < 4; ++kt)
        #pragma unroll
        for (int p = 0; p < 4; ++p) {
            int k = kt * 16 + q * 4 + p;
            float wv = WhhS[k * 64 + w * 16 + c];
            Wint[kt][2 * p]     = (_Float16)wv;
            Wint[kt][2 * p + 1] = (_Float16)(wv * 0.015625f);
            float dv = (c < 10) ? WdS[k * 10 + c] : 0.f;
            Wdint[kt][2 * p]     = (_Float16)dv;
            Wdint[kt][2 * p + 1] = (_Float16)(dv * 0.015625f);
        }
    #pragma unroll
    for (int j = 0; j < 8; ++j) {
        int i2 = qs + j;
        float pv = (i2 < 10) ? P1t[i2 * 64 + w * 16 + c]
                 : (i2 < 20) ? P2t[(i2 - 10) * 64 + w * 16 + c] : 0.f;
        Pf[j] = (_Float16)pv;
    }
    float bdv = (c < 10) ? bd[c] : 0.f;
    const bool cLt10 = (c < 10);
    __syncthreads();   // staging region free for ring reuse

    // ---- zero slot 15 (h_{-1}=0) ----
    for (int i = tid; i < 1088; i += 256) pool[15 * 1088 + i] = 0;
    __syncthreads();

    // ---- loop-invariant addresses (dword units) ----
    const int rBase = c * 68 + q * 4;
    const int wBase = (q * 4) * 68 + w * 16 + c;
    int projBase[2];
    projBase[0] = (2 * w + 0) * 1088 + rBase;
    projBase[1] = (2 * w + 1) * 1088 + rBase;

    float* outP[2][4];
    #pragma unroll
    for (int u = 0; u < 2; ++u)
        #pragma unroll
        for (int r = 0; r < 4; ++r)
            outP[u][r] = out + (((g * 16 + q * 4 + r) * 128) + 2 * w + u) * 10 + c;

    const floatx4 zero4 = {0.f, 0.f, 0.f, 0.f};

    // ---- prologue: Cxp for t=0; mask for t=1 ----
    floatx4 Cxp;
    {
        int mk0 = numpk[c];
        half8 Aoh = *(const half8*)&lutI[((mk0 >> qs) & 0xFF) * 4];
        Cxp = MFMA16(Aoh, Pf, zero4);
    }
    int mkN = numpk[16 + c];
    const int* npP = numpk + c;

    #define ADV() do { _Pragma("unroll") for (int u_ = 0; u_ < 2; ++u_) \
        { _Pragma("unroll") for (int r_ = 0; r_ < 4; ++r_) outP[u_][r_] += 80; } } while (0)

    // half 0 (SB=0, no projection yet)
    steps8<0, false>(pool, lutI, npP, Wint, Wdint, Pf, Cxp, mkN,
                     rBase, wBase, qs, projBase, bdv, cLt10, outP);
    ADV(); npP += 128;

    // halves 1..14
    #pragma unroll 1
    for (int hh = 0; hh < 7; ++hh) {
        steps8<8, true>(pool, lutI, npP, Wint, Wdint, Pf, Cxp, mkN,
                        rBase, wBase, qs, projBase, bdv, cLt10, outP);
        ADV(); npP += 128;
        steps8<0, true>(pool, lutI, npP, Wint, Wdint, Pf, Cxp, mkN,
                        rBase, wBase, qs, projBase, bdv, cLt10, outP);
        ADV(); npP += 128;
    }
    // half 15
    steps8<8, true>(pool, lutI, npP, Wint, Wdint, Pf, Cxp, mkN,
                    rBase, wBase, qs, projBase, bdv, cLt10, outP);
    ADV();
    #undef ADV

    // ---- epilogue: steps 120..127 (slots 8..15) ----
    #pragma unroll
    for (int u = 0; u < 2; ++u) {
        const int sl = projBase[u] + 8 * 1088;
        half8 P0 = *(const half8*)&pool[sl];
        half8 P1 = *(const half8*)&pool[sl + 16];
        half8 P2 = *(const half8*)&pool[sl + 32];
        half8 P3 = *(const half8*)&pool[sl + 48];
        floatx4 Cp = MFMA16(P0, Wdint[0], zero4);
        Cp         = MFMA16(P1, Wdint[1], Cp);
        Cp         = MFMA16(P2, Wdint[2], Cp);
        Cp         = MFMA16(P3, Wdint[3], Cp);
        if (cLt10) {
            #pragma unroll
            for (int r = 0; r < 4; ++r)
                outP[u][r][-80] = Cp[r] + bdv;
        }
    }
}

extern "C" void kernel_launch(void* const* d_in, const int* in_sizes, int n_in,
                              void* d_out, int out_size, void* d_ws, size_t ws_size,
                              hipStream_t stream) {
    const int*   num1 = (const int*)d_in[0];
    const int*   num2 = (const int*)d_in[1];
    const float* E    = (const float*)d_in[2];
    const float* Wxh  = (const float*)d_in[3];
    const float* Whh  = (const float*)d_in[4];
    const float* b    = (const float*)d_in[5];
    const float* Wd   = (const float*)d_in[6];
    const float* bd   = (const float*)d_in[7];
    float* out = (float*)d_out;
    rnn_mfma<<<256, 256, 0, stream>>>(num1, num2, E, Wxh, Whh, b, Wd, bd, out);
}